// Round 5
// baseline (1535.963 us; speedup 1.0000x reference)
//
#include <hip/hip_runtime.h>
#include <math.h>

#define NC_   100000
#define ND_   100000
#define NN_   100000   // == NC_ == ND_
#define E_CNT 500000
#define L_CNT 100000
#define NH_   4
#define HD_   32

__device__ __forceinline__ float gelu_f(float x) {
    const float c0 = 0.7978845608028654f; // sqrt(2/pi)
    float x3 = x * x * x;
    return 0.5f * x * (1.0f + tanhf(c0 * (x + 0.044715f * x3)));
}

// ======================= CSR build (counting sort by dst) =======================
__global__ __launch_bounds__(256) void fill0_int(int* __restrict__ p, int n) {
    int i = blockIdx.x * 256 + threadIdx.x;
    if (i < n) p[i] = 0;
}

__global__ __launch_bounds__(256) void count_dst(const int* __restrict__ dst,
                                                 int* __restrict__ cnt) {
    int e = blockIdx.x * 256 + threadIdx.x;
    if (e < E_CNT) atomicAdd(&cnt[dst[e]], 1);
}

__global__ __launch_bounds__(256) void scan_a(const int* __restrict__ cnt,
                                              int* __restrict__ excl,
                                              int* __restrict__ partials) {
    __shared__ int sd[256];
    int b = blockIdx.x, t = threadIdx.x;
    int base = b * 1024 + t * 4;
    int v0 = (base + 0 < NN_) ? cnt[base + 0] : 0;
    int v1 = (base + 1 < NN_) ? cnt[base + 1] : 0;
    int v2 = (base + 2 < NN_) ? cnt[base + 2] : 0;
    int v3 = (base + 3 < NN_) ? cnt[base + 3] : 0;
    int tsum = v0 + v1 + v2 + v3;
    sd[t] = tsum; __syncthreads();
    for (int off = 1; off < 256; off <<= 1) {
        int x = (t >= off) ? sd[t - off] : 0;
        __syncthreads();
        sd[t] += x;
        __syncthreads();
    }
    int excl_t = sd[t] - tsum;
    if (t == 255) partials[b] = sd[t];
    int r = excl_t;
    if (base + 0 < NN_) excl[base + 0] = r; r += v0;
    if (base + 1 < NN_) excl[base + 1] = r; r += v1;
    if (base + 2 < NN_) excl[base + 2] = r; r += v2;
    if (base + 3 < NN_) excl[base + 3] = r;
}

__global__ __launch_bounds__(128) void scan_b(int* __restrict__ partials) {
    __shared__ int sd[128];
    int t = threadIdx.x;
    int orig = (t < 98) ? partials[t] : 0;
    sd[t] = orig; __syncthreads();
    for (int off = 1; off < 128; off <<= 1) {
        int x = (t >= off) ? sd[t - off] : 0;
        __syncthreads();
        sd[t] += x;
        __syncthreads();
    }
    if (t < 98) partials[t] = sd[t] - orig;
}

__global__ __launch_bounds__(256) void scan_c(int* __restrict__ row_ptr,
                                              const int* __restrict__ partials,
                                              int* __restrict__ cursor) {
    int b = blockIdx.x, t = threadIdx.x;
    int base = b * 1024 + t * 4;
    int add = partials[b];
    #pragma unroll
    for (int j = 0; j < 4; j++) {
        int i = base + j;
        if (i < NN_) { int v = row_ptr[i] + add; row_ptr[i] = v; cursor[i] = v; }
    }
    if (b == 0 && t == 0) row_ptr[NN_] = E_CNT;
}

__global__ __launch_bounds__(256) void scatter_edges(const int* __restrict__ src,
                                                     const int* __restrict__ dst,
                                                     int* __restrict__ cursor,
                                                     int* __restrict__ srcs) {
    int e = blockIdx.x * 256 + threadIdx.x;
    if (e >= E_CNT) return;
    int pos = atomicAdd(&cursor[dst[e]], 1);
    srcs[pos] = src[e];
}

// ======================= weight fusion =======================
// Wcat: 128 rows x 384 cols, bias row at 128:
//   cols [0,128): qW+qb | [128,256): kW@blockdiag(arel) | [256,384): vW@blockdiag(mrel)
__global__ void fuse_weights(const float* __restrict__ qW, const float* __restrict__ qb,
                             const float* __restrict__ kW, const float* __restrict__ kb,
                             const float* __restrict__ vW, const float* __restrict__ vb,
                             const float* __restrict__ arel, const float* __restrict__ mrel,
                             float* __restrict__ WcatC, float* __restrict__ WcatD)
{
    int i  = blockIdx.x;   // 0..128 (128 == bias row)
    int t  = blockIdx.y;
    int oc = threadIdx.x;  // 0..383
    float* Wcat = t ? WcatD : WcatC;
    float val;
    if (oc < 128) {
        val = (i < 128) ? qW[(t * 128 + i) * 128 + oc] : qb[t * 128 + oc];
    } else {
        int which = (oc >= 256);
        int cc = oc - (which ? 256 : 128);
        int h = cc >> 5, e = cc & 31;
        const float* W = which ? vW : kW;
        const float* b = which ? vb : kb;
        const float* R = (which ? mrel : arel) + (size_t)(t * NH_ + h) * HD_ * HD_ + e;
        float s = 0.f;
        if (i < 128) {
            const float* wrow = W + (size_t)(t * 128 + i) * 128 + h * 32;
            #pragma unroll
            for (int d2 = 0; d2 < 32; d2++) s += wrow[d2] * R[d2 * 32];
        } else {
            const float* brow = b + t * 128 + h * 32;
            #pragma unroll
            for (int d2 = 0; d2 < 32; d2++) s += brow[d2] * R[d2 * 32];
        }
        val = s;
    }
    Wcat[(size_t)((i < 128) ? i : 128) * 384 + oc] = val;
}

// ======================= fp32 tiled GEMM v2 =======================
// C[M,N] = act(A[M,128] @ B[128,N] + bias); tile 128 x TN, BK=16,
// 8 x (TN/16) register blocking, 256 threads.
// PREACT: gelu on A load. POST: C = relu(g*v + (1-g)*resid) (resid may alias C).
template<int TN, int PREACT, int POST>
__global__ __launch_bounds__(256)
void gemm2(const float* __restrict__ A, int lda,
           const float* __restrict__ B, int ldb,
           const float* __restrict__ bias,
           float* __restrict__ C, int ldc,
           int M,
           const float* __restrict__ resid,
           const float* __restrict__ skipv)
{
    constexpr int TC = TN / 16;         // cols per thread (8 or 4)
    constexpr int BSTR = TN + 4;        // padded LDS row stride
    __shared__ float As[16][132];       // [k][m]
    __shared__ float Bs[16][BSTR];      // [k][n]
    int tid = threadIdx.x;
    int tx = tid & 15, ty = tid >> 4;
    int bm = blockIdx.x * 128;
    int bn = blockIdx.y * TN;
    float acc[8][TC];
    #pragma unroll
    for (int i = 0; i < 8; i++)
        #pragma unroll
        for (int j = 0; j < TC; j++) acc[i][j] = 0.f;

    // A staging: thread loads 8 k-consecutive floats of row m_a
    int m_a  = tid >> 1;                // 0..127
    int koff = (tid & 1) * 8;           // 0 or 8
    int arow = bm + m_a;
    bool avalid = arow < M;
    const float* aptr = A + (size_t)arow * lda + koff;
    // B staging: thread loads TC floats of row k_b
    int k_b = tid >> 4;                 // 0..15
    int bn4 = (tid & 15) * TC;
    const float* bptr = B + (size_t)k_b * ldb + bn + bn4;

    for (int k0 = 0; k0 < 128; k0 += 16) {
        float4 a0 = make_float4(0.f,0.f,0.f,0.f), a1 = a0;
        if (avalid) {
            a0 = *(const float4*)(aptr + k0);
            a1 = *(const float4*)(aptr + k0 + 4);
        }
        if (PREACT) {
            a0.x = gelu_f(a0.x); a0.y = gelu_f(a0.y); a0.z = gelu_f(a0.z); a0.w = gelu_f(a0.w);
            a1.x = gelu_f(a1.x); a1.y = gelu_f(a1.y); a1.z = gelu_f(a1.z); a1.w = gelu_f(a1.w);
        }
        float4 b0 = *(const float4*)(bptr + (size_t)k0 * ldb);
        float4 b1;
        if (TC == 8) b1 = *(const float4*)(bptr + (size_t)k0 * ldb + 4);
        __syncthreads();
        As[koff + 0][m_a] = a0.x; As[koff + 1][m_a] = a0.y;
        As[koff + 2][m_a] = a0.z; As[koff + 3][m_a] = a0.w;
        As[koff + 4][m_a] = a1.x; As[koff + 5][m_a] = a1.y;
        As[koff + 6][m_a] = a1.z; As[koff + 7][m_a] = a1.w;
        *(float4*)&Bs[k_b][bn4] = b0;
        if (TC == 8) *(float4*)&Bs[k_b][bn4 + 4] = b1;
        __syncthreads();
        #pragma unroll
        for (int kk = 0; kk < 16; kk++) {
            float a[8], b[TC];
            #pragma unroll
            for (int i = 0; i < 8; i += 4)
                *(float4*)&a[i] = *(const float4*)&As[kk][ty * 8 + i];
            #pragma unroll
            for (int j = 0; j < TC; j += 4)
                *(float4*)&b[j] = *(const float4*)&Bs[kk][tx * TC + j];
            #pragma unroll
            for (int i = 0; i < 8; i++)
                #pragma unroll
                for (int j = 0; j < TC; j++)
                    acc[i][j] += a[i] * b[j];
        }
    }

    float g = 0.f, omg = 0.f;
    if (POST) { float sv = skipv[0]; g = 1.0f / (1.0f + expf(-sv)); omg = 1.0f - g; }
    float bb[TC];
    #pragma unroll
    for (int j = 0; j < TC; j++) bb[j] = bias[bn + tx * TC + j];
    #pragma unroll
    for (int i = 0; i < 8; i++) {
        int m = bm + ty * 8 + i;
        if (m >= M) continue;
        float* crow = C + (size_t)m * ldc + bn + tx * TC;
        const float* rrow = POST ? (resid + (size_t)m * ldc + bn + tx * TC) : nullptr;
        #pragma unroll
        for (int j = 0; j < TC; j += 4) {
            float4 r;
            if (POST) r = *(const float4*)(rrow + j);
            float4 v;
            v.x = acc[i][j + 0] + bb[j + 0];
            v.y = acc[i][j + 1] + bb[j + 1];
            v.z = acc[i][j + 2] + bb[j + 2];
            v.w = acc[i][j + 3] + bb[j + 3];
            if (POST) {
                v.x = fmaxf(g * v.x + omg * r.x, 0.f);
                v.y = fmaxf(g * v.y + omg * r.y, 0.f);
                v.z = fmaxf(g * v.z + omg * r.z, 0.f);
                v.w = fmaxf(g * v.w + omg * r.w, 0.f);
            }
            *(float4*)(crow + j) = v;
        }
    }
}

// ======================= fused attention gather v2 =======================
// One wave per dst node, TWO edges in flight (group = lane>>5).
// Within a 32-lane group: head h = (lane&31)>>3, lane holds dims [gl*4, gl*4+4).
// qo: [Nd,128] holds dst q on entry, attention output on exit.
// kv: [Ns,256] = [krel(128) | vrel(128)]. Online softmax; merge groups at end.
__global__ __launch_bounds__(256)
void attn_gather(const int* __restrict__ row_ptr, const int* __restrict__ srcs,
                 float* __restrict__ qo, const float* __restrict__ kv,
                 const float* __restrict__ prel, int ndst)
{
    int wave = (blockIdx.x * 256 + threadIdx.x) >> 6;
    int lane = threadIdx.x & 63;
    if (wave >= ndst) return;
    int d = wave;
    int gl = lane & 31;
    int group = lane >> 5;
    int h = gl >> 3;
    float pr = prel[h] * 0.17677669529663687f;  // prel / sqrt(32)
    int beg = row_ptr[d], end = row_ptr[d + 1];
    float4 qv = *(const float4*)(qo + (size_t)d * 128 + gl * 4);
    float m = -1.0e30f, l = 0.f;
    float4 acc = make_float4(0.f, 0.f, 0.f, 0.f);
    int nt = (end - beg + 1) >> 1;
    for (int t = 0; t < nt; t++) {
        int i = beg + (t << 1) + group;
        if (i < end) {
            int s = srcs[i];
            const float* row = kv + (size_t)s * 256;
            float4 kvv = *(const float4*)(row + gl * 4);
            float4 vv  = *(const float4*)(row + 128 + gl * 4);
            float part = qv.x * kvv.x + qv.y * kvv.y + qv.z * kvv.z + qv.w * kvv.w;
            part += __shfl_xor(part, 1);
            part += __shfl_xor(part, 2);
            part += __shfl_xor(part, 4);   // 8 lanes of (group,head) hold the dot
            float a = part * pr;
            float mn = fmaxf(m, a);
            float scale = expf(m - mn);
            float p = expf(a - mn);
            l = l * scale + p;
            acc.x = acc.x * scale + p * vv.x;
            acc.y = acc.y * scale + p * vv.y;
            acc.z = acc.z * scale + p * vv.z;
            acc.w = acc.w * scale + p * vv.w;
            m = mn;
        }
    }
    // merge the two edge-groups' online-softmax states
    float m_o = __shfl_xor(m, 32);
    float l_o = __shfl_xor(l, 32);
    float4 acc_o;
    acc_o.x = __shfl_xor(acc.x, 32);
    acc_o.y = __shfl_xor(acc.y, 32);
    acc_o.z = __shfl_xor(acc.z, 32);
    acc_o.w = __shfl_xor(acc.w, 32);
    float mn = fmaxf(m, m_o);
    float s0 = expf(m - mn), s1 = expf(m_o - mn);
    float lt = l * s0 + l_o * s1;
    float inv = 1.f / (lt + 1e-16f);
    if (beg == end) inv = 0.f;
    float4 o;
    o.x = (acc.x * s0 + acc_o.x * s1) * inv;
    o.y = (acc.y * s0 + acc_o.y * s1) * inv;
    o.z = (acc.z * s0 + acc_o.z * s1) * inv;
    o.w = (acc.w * s0 + acc_o.w * s1) * inv;
    if (group == 0)
        *(float4*)(qo + (size_t)d * 128 + gl * 4) = o;
}

// ======================= final scoring =======================
__global__ __launch_bounds__(256)
void score_pairs(const int* __restrict__ ic, const int* __restrict__ id,
                 const float* __restrict__ zC, const float* __restrict__ zD,
                 float* __restrict__ out)
{
    int gid = blockIdx.x * 256 + threadIdx.x;
    int p = gid >> 4, lane = gid & 15;
    if (p >= L_CNT) return;
    int c = ic[p], d = id[p];
    float4 a = *(const float4*)(zC + (size_t)c * 64 + lane * 4);
    float4 b = *(const float4*)(zD + (size_t)d * 64 + lane * 4);
    float s = a.x * b.x + a.y * b.y + a.z * b.z + a.w * b.w;
    s += __shfl_down(s, 8, 16);
    s += __shfl_down(s, 4, 16);
    s += __shfl_down(s, 2, 16);
    s += __shfl_down(s, 1, 16);
    if (lane == 0) out[p] = fminf(10.0f, fmaxf(-10.0f, s));
}

extern "C" void kernel_launch(void* const* d_in, const int* in_sizes, int n_in,
                              void* d_out, int out_size, void* d_ws, size_t ws_size,
                              hipStream_t stream)
{
    // Persistent node states live in the emb input buffers (harness restores
    // d_in from pristine copies before every timed launch).
    float* xC = (float*)d_in[0];
    float* xD = (float*)d_in[1];
    const float* kW   = (const float*)d_in[2];
    const float* kb   = (const float*)d_in[3];
    const float* qW   = (const float*)d_in[4];
    const float* qb   = (const float*)d_in[5];
    const float* vW   = (const float*)d_in[6];
    const float* vb   = (const float*)d_in[7];
    const float* aW   = (const float*)d_in[8];
    const float* ab   = (const float*)d_in[9];
    const float* skip = (const float*)d_in[10];
    const float* arel = (const float*)d_in[11];
    const float* mrel = (const float*)d_in[12];
    const float* prel = (const float*)d_in[13];
    const float* outW = (const float*)d_in[14];
    const float* outb = (const float*)d_in[15];
    const int* ei_cd  = (const int*)d_in[16];
    const int* ei_dc  = (const int*)d_in[17];
    const int* eli    = (const int*)d_in[18];

    // ---- workspace: 38.5M floats (154MB) + 1.4M ints (5.6MB) ----
    float* ws = (float*)d_ws;
    size_t off = 0;
    float* kv    = ws + off; off += (size_t)NN_ * 256;   // 25.6M  src [k|v]
    float* qo    = ws + off; off += (size_t)NN_ * 128;   // 12.8M  dst q -> attn out
    float* WcatC = ws + off; off += (size_t)129 * 384;
    float* WcatD = ws + off; off += (size_t)129 * 384;
    int* iws = (int*)(ws + off);
    size_t ioff = 0;
    int* rp_cd   = iws + ioff; ioff += NN_ + 1;
    int* rp_dc   = iws + ioff; ioff += NN_ + 1;
    int* srcs_cd = iws + ioff; ioff += E_CNT;
    int* srcs_dc = iws + ioff; ioff += E_CNT;
    int* cnt     = iws + ioff; ioff += NN_;
    int* cursor  = iws + ioff; ioff += NN_;
    int* partial = iws + ioff; ioff += 128;
    float* zC = kv;                                      // reuse after edge phases
    float* zD = kv + (size_t)NN_ * 128;

    const int gridM = (NN_ + 127) / 128;          // 782
    const int gE    = (E_CNT + 255) / 256;
    const int gN    = (NN_ + 255) / 256;
    const int gScan = 98;
    const int gGath = (NN_ + 3) / 4;              // 4 waves/block

    // ---- build CSR for both relations ----
    {
        const int* srcs[2] = { ei_cd, ei_dc };
        const int* dsts[2] = { ei_cd + E_CNT, ei_dc + E_CNT };
        int* rps[2]  = { rp_cd, rp_dc };
        int* outs[2] = { srcs_cd, srcs_dc };
        for (int r = 0; r < 2; r++) {
            fill0_int<<<gN, 256, 0, stream>>>(cnt, NN_);
            count_dst<<<gE, 256, 0, stream>>>(dsts[r], cnt);
            scan_a<<<gScan, 256, 0, stream>>>(cnt, rps[r], partial);
            scan_b<<<1, 128, 0, stream>>>(partial);
            scan_c<<<gScan, 256, 0, stream>>>(rps[r], partial, cursor);
            scatter_edges<<<gE, 256, 0, stream>>>(srcs[r], dsts[r], cursor, outs[r]);
        }
    }

    for (int l = 0; l < 2; l++) {
        const float* aWl = aW + (size_t)l * 2 * 128 * 128;
        const float* abl = ab + (size_t)l * 2 * 128;

        fuse_weights<<<dim3(129, 2), 384, 0, stream>>>(
            qW + (size_t)l * 2 * 128 * 128, qb + (size_t)l * 2 * 128,
            kW + (size_t)l * 2 * 128 * 128, kb + (size_t)l * 2 * 128,
            vW + (size_t)l * 2 * 128 * 128, vb + (size_t)l * 2 * 128,
            arel + (size_t)l * 2 * NH_ * HD_ * HD_,
            mrel + (size_t)l * 2 * NH_ * HD_ * HD_, WcatC, WcatD);

        // ---- relation 0: C -> D ----
        gemm2<128, 0, 0><<<dim3(gridM, 2), 256, 0, stream>>>(     // kvC
            xC, 128, WcatC + 128, 384, WcatC + 128 * 384 + 128, kv, 256, NC_, nullptr, nullptr);
        gemm2<128, 0, 0><<<dim3(gridM, 1), 256, 0, stream>>>(     // qD
            xD, 128, WcatD, 384, WcatD + 128 * 384, qo, 128, ND_, nullptr, nullptr);
        attn_gather<<<gGath, 256, 0, stream>>>(rp_cd, srcs_cd, qo, kv,
                                               prel + (l * 2 + 0) * 4, ND_);  // outD in qo

        // kvD from OLD xD (before epilogue D overwrites it)
        gemm2<128, 0, 0><<<dim3(gridM, 2), 256, 0, stream>>>(
            xD, 128, WcatD + 128, 384, WcatD + 128 * 384 + 128, kv, 256, ND_, nullptr, nullptr);

        // epilogue D: xD = relu(g*(gelu(outD)@aW_D+ab_D) + (1-g)*xD)
        gemm2<128, 1, 1><<<dim3(gridM, 1), 256, 0, stream>>>(
            qo, 128, aWl + 128 * 128, 128, abl + 128, xD, 128, ND_, xD, skip + l * 2 + 1);

        // ---- relation 1: D -> C ----
        gemm2<128, 0, 0><<<dim3(gridM, 1), 256, 0, stream>>>(     // qC (old xC)
            xC, 128, WcatC, 384, WcatC + 128 * 384, qo, 128, NC_, nullptr, nullptr);
        attn_gather<<<gGath, 256, 0, stream>>>(rp_dc, srcs_dc, qo, kv,
                                               prel + (l * 2 + 1) * 4, NC_);  // outC in qo

        // epilogue C
        gemm2<128, 1, 1><<<dim3(gridM, 1), 256, 0, stream>>>(
            qo, 128, aWl, 128, abl, xC, 128, NC_, xC, skip + l * 2 + 0);
    }

    // final projections z = x @ outW + outb  ([N,128] @ [128,64])
    gemm2<64, 0, 0><<<dim3(gridM, 1), 256, 0, stream>>>(
        xC, 128, outW, 64, outb, zC, 64, NC_, nullptr, nullptr);
    gemm2<64, 0, 0><<<dim3(gridM, 1), 256, 0, stream>>>(
        xD, 128, outW + 128 * 64, 64, outb + 64, zD, 64, ND_, nullptr, nullptr);

    score_pairs<<<(L_CNT * 16 + 255) / 256, 256, 0, stream>>>(
        eli, eli + L_CNT, zC, zD, (float*)d_out);
}

// Round 6
// 1424.482 us; speedup vs baseline: 1.0783x; 1.0783x over previous
//
#include <hip/hip_runtime.h>
#include <math.h>

#define NC_   100000
#define ND_   100000
#define NN_   100000   // == NC_ == ND_
#define E_CNT 500000
#define L_CNT 100000
#define NH_   4
#define HD_   32
#define WCAT_SZ (129 * 384)

__device__ __forceinline__ float gelu_f(float x) {
    const float c0 = 0.7978845608028654f; // sqrt(2/pi)
    float x3 = x * x * x;
    return 0.5f * x * (1.0f + tanhf(c0 * (x + 0.044715f * x3)));
}

// ======================= CSR build (counting sort by dst) =======================
__global__ __launch_bounds__(256) void fill0_int(int* __restrict__ p, int n) {
    int i = blockIdx.x * 256 + threadIdx.x;
    if (i < n) p[i] = 0;
}

__global__ __launch_bounds__(256) void count_dst(const int* __restrict__ dst,
                                                 int* __restrict__ cnt) {
    int e = blockIdx.x * 256 + threadIdx.x;
    if (e < E_CNT) atomicAdd(&cnt[dst[e]], 1);
}

__global__ __launch_bounds__(256) void scan_a(const int* __restrict__ cnt,
                                              int* __restrict__ excl,
                                              int* __restrict__ partials) {
    __shared__ int sd[256];
    int b = blockIdx.x, t = threadIdx.x;
    int base = b * 1024 + t * 4;
    int v0 = (base + 0 < NN_) ? cnt[base + 0] : 0;
    int v1 = (base + 1 < NN_) ? cnt[base + 1] : 0;
    int v2 = (base + 2 < NN_) ? cnt[base + 2] : 0;
    int v3 = (base + 3 < NN_) ? cnt[base + 3] : 0;
    int tsum = v0 + v1 + v2 + v3;
    sd[t] = tsum; __syncthreads();
    for (int off = 1; off < 256; off <<= 1) {
        int x = (t >= off) ? sd[t - off] : 0;
        __syncthreads();
        sd[t] += x;
        __syncthreads();
    }
    int excl_t = sd[t] - tsum;
    if (t == 255) partials[b] = sd[t];
    int r = excl_t;
    if (base + 0 < NN_) excl[base + 0] = r; r += v0;
    if (base + 1 < NN_) excl[base + 1] = r; r += v1;
    if (base + 2 < NN_) excl[base + 2] = r; r += v2;
    if (base + 3 < NN_) excl[base + 3] = r;
}

__global__ __launch_bounds__(128) void scan_b(int* __restrict__ partials) {
    __shared__ int sd[128];
    int t = threadIdx.x;
    int orig = (t < 98) ? partials[t] : 0;
    sd[t] = orig; __syncthreads();
    for (int off = 1; off < 128; off <<= 1) {
        int x = (t >= off) ? sd[t - off] : 0;
        __syncthreads();
        sd[t] += x;
        __syncthreads();
    }
    if (t < 98) partials[t] = sd[t] - orig;
}

__global__ __launch_bounds__(256) void scan_c(int* __restrict__ row_ptr,
                                              const int* __restrict__ partials,
                                              int* __restrict__ cursor) {
    int b = blockIdx.x, t = threadIdx.x;
    int base = b * 1024 + t * 4;
    int add = partials[b];
    #pragma unroll
    for (int j = 0; j < 4; j++) {
        int i = base + j;
        if (i < NN_) { int v = row_ptr[i] + add; row_ptr[i] = v; cursor[i] = v; }
    }
    if (b == 0 && t == 0) row_ptr[NN_] = E_CNT;
}

__global__ __launch_bounds__(256) void scatter_edges(const int* __restrict__ src,
                                                     const int* __restrict__ dst,
                                                     int* __restrict__ cursor,
                                                     int* __restrict__ srcs) {
    int e = blockIdx.x * 256 + threadIdx.x;
    if (e >= E_CNT) return;
    int pos = atomicAdd(&cursor[dst[e]], 1);
    srcs[pos] = src[e];
}

// ======================= weight fusion (both layers in one launch) ==============
// Wcat[l*2+t]: 128 rows x 384 cols, bias row at 128:
//   cols [0,128): qW+qb | [128,256): kW@blockdiag(arel) | [256,384): vW@blockdiag(mrel)
__global__ void fuse_weights(const float* __restrict__ qW, const float* __restrict__ qb,
                             const float* __restrict__ kW, const float* __restrict__ kb,
                             const float* __restrict__ vW, const float* __restrict__ vb,
                             const float* __restrict__ arel, const float* __restrict__ mrel,
                             float* __restrict__ WcatAll)
{
    int i  = blockIdx.x;   // 0..128 (128 == bias row)
    int t  = blockIdx.y;   // node type (== relation whose src is t)
    int lyr = blockIdx.z;  // layer
    int oc = threadIdx.x;  // 0..383
    int lt = lyr * 2 + t;
    float* Wcat = WcatAll + (size_t)lt * WCAT_SZ;
    float val;
    if (oc < 128) {
        val = (i < 128) ? qW[(size_t)(lt * 128 + i) * 128 + oc] : qb[lt * 128 + oc];
    } else {
        int which = (oc >= 256);
        int cc = oc - (which ? 256 : 128);
        int h = cc >> 5, e = cc & 31;
        const float* W = which ? vW : kW;
        const float* b = which ? vb : kb;
        const float* R = (which ? mrel : arel) + (size_t)(lt * NH_ + h) * HD_ * HD_ + e;
        float s = 0.f;
        if (i < 128) {
            const float* wrow = W + (size_t)(lt * 128 + i) * 128 + h * 32;
            #pragma unroll
            for (int d2 = 0; d2 < 32; d2++) s += wrow[d2] * R[d2 * 32];
        } else {
            const float* brow = b + lt * 128 + h * 32;
            #pragma unroll
            for (int d2 = 0; d2 < 32; d2++) s += brow[d2] * R[d2 * 32];
        }
        val = s;
    }
    Wcat[(size_t)((i < 128) ? i : 128) * 384 + oc] = val;
}

// ======================= fp32 tiled GEMM v3 =======================
// C[M,N] = act(A[M,128] @ B[128,N] + bias); tile 128 x TN, BK=16, 256 threads,
// 8 x (TN/16) register blocking. Conflict-free LDS mapping (2-way aliasing only):
// thread's columns are {tx*4..+3} (+ {64+tx*4..+3} for TN=128).
// Software-pipelined staging: next K-slab's global loads issue before compute.
// Optional second problem (ySplit>=0): blocks with blockIdx.y>=ySplit use *2 ptrs.
template<int TN, int PREACT, int POST>
__global__ __launch_bounds__(256)
void gemm2(const float* __restrict__ A, int lda,
           const float* __restrict__ B, int ldb,
           const float* __restrict__ bias,
           float* __restrict__ C, int ldc,
           int M,
           const float* __restrict__ resid,
           const float* __restrict__ skipv,
           int ySplit,
           const float* __restrict__ A2, const float* __restrict__ B2,
           const float* __restrict__ bias2, float* __restrict__ C2, int ldc2)
{
    constexpr int TC = TN / 16;         // cols per thread (8 or 4)
    __shared__ float As[16][132];       // [k][m]
    __shared__ float Bs[16][TN + 4];    // [k][n]
    int by = blockIdx.y;
    if (ySplit >= 0 && by >= ySplit) {
        A = A2; B = B2; bias = bias2; C = C2; ldc = ldc2; by -= ySplit;
    }
    int tid = threadIdx.x;
    int tx = tid & 15, ty = tid >> 4;
    int bm = blockIdx.x * 128;
    int bn = by * TN;
    float acc[8][TC];
    #pragma unroll
    for (int i = 0; i < 8; i++)
        #pragma unroll
        for (int j = 0; j < TC; j++) acc[i][j] = 0.f;

    // A staging: thread loads 8 k-consecutive floats of row m_a
    int m_a  = tid >> 1;                // 0..127
    int koff = (tid & 1) * 8;           // 0 or 8
    int arow = bm + m_a;
    bool avalid = arow < M;
    const float* aptr = A + (size_t)arow * lda + koff;
    // B staging: thread loads cols {txs*4..+3} (+ {64+txs*4..+3}) of row k_b
    int k_b = tid >> 4;                 // 0..15
    int txs = tid & 15;
    const float* bptr = B + (size_t)k_b * ldb + bn + txs * 4;

    // prologue: load K-slab 0
    float4 a0 = make_float4(0.f,0.f,0.f,0.f), a1 = a0, b0, b1;
    if (avalid) { a0 = *(const float4*)(aptr); a1 = *(const float4*)(aptr + 4); }
    b0 = *(const float4*)(bptr);
    if (TC == 8) b1 = *(const float4*)(bptr + 64);

    for (int k0 = 0; k0 < 128; k0 += 16) {
        if (PREACT) {
            a0.x = gelu_f(a0.x); a0.y = gelu_f(a0.y); a0.z = gelu_f(a0.z); a0.w = gelu_f(a0.w);
            a1.x = gelu_f(a1.x); a1.y = gelu_f(a1.y); a1.z = gelu_f(a1.z); a1.w = gelu_f(a1.w);
        }
        __syncthreads();
        As[koff + 0][m_a] = a0.x; As[koff + 1][m_a] = a0.y;
        As[koff + 2][m_a] = a0.z; As[koff + 3][m_a] = a0.w;
        As[koff + 4][m_a] = a1.x; As[koff + 5][m_a] = a1.y;
        As[koff + 6][m_a] = a1.z; As[koff + 7][m_a] = a1.w;
        *(float4*)&Bs[k_b][txs * 4] = b0;
        if (TC == 8) *(float4*)&Bs[k_b][64 + txs * 4] = b1;
        __syncthreads();
        // prefetch next slab (latency hidden behind the FMA block below)
        if (k0 + 16 < 128) {
            if (avalid) {
                a0 = *(const float4*)(aptr + k0 + 16);
                a1 = *(const float4*)(aptr + k0 + 20);
            }
            b0 = *(const float4*)(bptr + (size_t)(k0 + 16) * ldb);
            if (TC == 8) b1 = *(const float4*)(bptr + (size_t)(k0 + 16) * ldb + 64);
        }
        #pragma unroll
        for (int kk = 0; kk < 16; kk++) {
            float a[8], b[TC];
            *(float4*)&a[0] = *(const float4*)&As[kk][ty * 8];
            *(float4*)&a[4] = *(const float4*)&As[kk][ty * 8 + 4];
            *(float4*)&b[0] = *(const float4*)&Bs[kk][tx * 4];
            if (TC == 8) *(float4*)&b[4] = *(const float4*)&Bs[kk][64 + tx * 4];
            #pragma unroll
            for (int i = 0; i < 8; i++)
                #pragma unroll
                for (int j = 0; j < TC; j++)
                    acc[i][j] += a[i] * b[j];
        }
    }

    float g = 0.f, omg = 0.f;
    if (POST) { float sv = skipv[0]; g = 1.0f / (1.0f + expf(-sv)); omg = 1.0f - g; }
    float bb[TC];
    #pragma unroll
    for (int j = 0; j < 4; j++) bb[j] = bias[bn + tx * 4 + j];
    if (TC == 8)
        #pragma unroll
        for (int j = 0; j < 4; j++) bb[4 + j] = bias[bn + 64 + tx * 4 + j];
    #pragma unroll
    for (int i = 0; i < 8; i++) {
        int m = bm + ty * 8 + i;
        if (m >= M) continue;
        #pragma unroll
        for (int half = 0; half < TC / 4; half++) {
            int coff = bn + half * 64 + tx * 4;
            float* crow = C + (size_t)m * ldc + coff;
            float4 v;
            v.x = acc[i][half * 4 + 0] + bb[half * 4 + 0];
            v.y = acc[i][half * 4 + 1] + bb[half * 4 + 1];
            v.z = acc[i][half * 4 + 2] + bb[half * 4 + 2];
            v.w = acc[i][half * 4 + 3] + bb[half * 4 + 3];
            if (POST) {
                float4 r = *(const float4*)(resid + (size_t)m * ldc + coff);
                v.x = fmaxf(g * v.x + omg * r.x, 0.f);
                v.y = fmaxf(g * v.y + omg * r.y, 0.f);
                v.z = fmaxf(g * v.z + omg * r.z, 0.f);
                v.w = fmaxf(g * v.w + omg * r.w, 0.f);
            }
            *(float4*)crow = v;
        }
    }
}

// ======================= fused attention gather v3 =======================
// One wave per dst node, FOUR edges in flight (group = lane>>4, 16 lanes/edge,
// 8 dims/lane). head h = (lane&15)>>2. Online softmax; hierarchical merge.
// qo: [Nd,128] dst q on entry, attention output on exit.
// kv: [Ns,256] = [krel(128) | vrel(128)].
__global__ __launch_bounds__(256)
void attn_gather(const int* __restrict__ row_ptr, const int* __restrict__ srcs,
                 float* __restrict__ qo, const float* __restrict__ kv,
                 const float* __restrict__ prel, int ndst)
{
    int wave = (blockIdx.x * 256 + threadIdx.x) >> 6;
    int lane = threadIdx.x & 63;
    if (wave >= ndst) return;
    int d = wave;
    int gl = lane & 15;            // lane within edge-group; dims [gl*8, gl*8+8)
    int group = lane >> 4;         // 0..3 edges in flight
    int h = gl >> 2;               // head
    float pr = prel[h] * 0.17677669529663687f;  // prel / sqrt(32)
    int beg = row_ptr[d], end = row_ptr[d + 1];
    const float* qrow = qo + (size_t)d * 128 + gl * 8;
    float4 q0 = *(const float4*)(qrow);
    float4 q1 = *(const float4*)(qrow + 4);
    float m = -1.0e30f, l = 0.f;
    float4 acc0 = make_float4(0.f,0.f,0.f,0.f), acc1 = acc0;
    int nt = (end - beg + 3) >> 2;
    for (int t = 0; t < nt; t++) {
        int i = beg + (t << 2) + group;
        if (i < end) {
            int s = srcs[i];
            const float* row = kv + (size_t)s * 256 + gl * 8;
            float4 k0 = *(const float4*)(row);
            float4 k1 = *(const float4*)(row + 4);
            float4 v0 = *(const float4*)(row + 128);
            float4 v1 = *(const float4*)(row + 132);
            float part = q0.x*k0.x + q0.y*k0.y + q0.z*k0.z + q0.w*k0.w
                       + q1.x*k1.x + q1.y*k1.y + q1.z*k1.z + q1.w*k1.w;
            part += __shfl_xor(part, 1);
            part += __shfl_xor(part, 2);   // 4 lanes of this head share the dot
            float a = part * pr;
            float mn = fmaxf(m, a);
            float scale = expf(m - mn);
            float p = expf(a - mn);
            l = l * scale + p;
            acc0.x = acc0.x * scale + p * v0.x;
            acc0.y = acc0.y * scale + p * v0.y;
            acc0.z = acc0.z * scale + p * v0.z;
            acc0.w = acc0.w * scale + p * v0.w;
            acc1.x = acc1.x * scale + p * v1.x;
            acc1.y = acc1.y * scale + p * v1.y;
            acc1.z = acc1.z * scale + p * v1.z;
            acc1.w = acc1.w * scale + p * v1.w;
            m = mn;
        }
    }
    // hierarchical merge of the 4 edge-groups' online-softmax states
    #pragma unroll
    for (int mask = 16; mask <= 32; mask <<= 1) {
        float m_o = __shfl_xor(m, mask);
        float l_o = __shfl_xor(l, mask);
        float4 a0o, a1o;
        a0o.x = __shfl_xor(acc0.x, mask); a0o.y = __shfl_xor(acc0.y, mask);
        a0o.z = __shfl_xor(acc0.z, mask); a0o.w = __shfl_xor(acc0.w, mask);
        a1o.x = __shfl_xor(acc1.x, mask); a1o.y = __shfl_xor(acc1.y, mask);
        a1o.z = __shfl_xor(acc1.z, mask); a1o.w = __shfl_xor(acc1.w, mask);
        float mn = fmaxf(m, m_o);
        float s0 = expf(m - mn), s1 = expf(m_o - mn);
        l = l * s0 + l_o * s1;
        acc0.x = acc0.x * s0 + a0o.x * s1; acc0.y = acc0.y * s0 + a0o.y * s1;
        acc0.z = acc0.z * s0 + a0o.z * s1; acc0.w = acc0.w * s0 + a0o.w * s1;
        acc1.x = acc1.x * s0 + a1o.x * s1; acc1.y = acc1.y * s0 + a1o.y * s1;
        acc1.z = acc1.z * s0 + a1o.z * s1; acc1.w = acc1.w * s0 + a1o.w * s1;
        m = mn;
    }
    float inv = (beg == end) ? 0.f : 1.f / (l + 1e-16f);
    if (group == 0) {
        float* orow = qo + (size_t)d * 128 + gl * 8;
        *(float4*)(orow)     = make_float4(acc0.x*inv, acc0.y*inv, acc0.z*inv, acc0.w*inv);
        *(float4*)(orow + 4) = make_float4(acc1.x*inv, acc1.y*inv, acc1.z*inv, acc1.w*inv);
    }
}

// ======================= final scoring =======================
__global__ __launch_bounds__(256)
void score_pairs(const int* __restrict__ ic, const int* __restrict__ id,
                 const float* __restrict__ zC, const float* __restrict__ zD,
                 float* __restrict__ out)
{
    int gid = blockIdx.x * 256 + threadIdx.x;
    int p = gid >> 4, lane = gid & 15;
    if (p >= L_CNT) return;
    int c = ic[p], d = id[p];
    float4 a = *(const float4*)(zC + (size_t)c * 64 + lane * 4);
    float4 b = *(const float4*)(zD + (size_t)d * 64 + lane * 4);
    float s = a.x * b.x + a.y * b.y + a.z * b.z + a.w * b.w;
    s += __shfl_down(s, 8, 16);
    s += __shfl_down(s, 4, 16);
    s += __shfl_down(s, 2, 16);
    s += __shfl_down(s, 1, 16);
    if (lane == 0) out[p] = fminf(10.0f, fmaxf(-10.0f, s));
}

extern "C" void kernel_launch(void* const* d_in, const int* in_sizes, int n_in,
                              void* d_out, int out_size, void* d_ws, size_t ws_size,
                              hipStream_t stream)
{
    // Persistent node states live in the emb input buffers (harness restores
    // d_in from pristine copies before every timed launch).
    float* xC = (float*)d_in[0];
    float* xD = (float*)d_in[1];
    const float* kW   = (const float*)d_in[2];
    const float* kb   = (const float*)d_in[3];
    const float* qW   = (const float*)d_in[4];
    const float* qb   = (const float*)d_in[5];
    const float* vW   = (const float*)d_in[6];
    const float* vb   = (const float*)d_in[7];
    const float* aW   = (const float*)d_in[8];
    const float* ab   = (const float*)d_in[9];
    const float* skip = (const float*)d_in[10];
    const float* arel = (const float*)d_in[11];
    const float* mrel = (const float*)d_in[12];
    const float* prel = (const float*)d_in[13];
    const float* outW = (const float*)d_in[14];
    const float* outb = (const float*)d_in[15];
    const int* ei_cd  = (const int*)d_in[16];
    const int* ei_dc  = (const int*)d_in[17];
    const int* eli    = (const int*)d_in[18];

    // ---- workspace: ~38.6M floats (155MB) + 1.4M ints (5.6MB) ----
    float* ws = (float*)d_ws;
    size_t off = 0;
    float* kv    = ws + off; off += (size_t)NN_ * 256;   // 25.6M  src [k|v]
    float* qo    = ws + off; off += (size_t)NN_ * 128;   // 12.8M  dst q -> attn out
    float* Wcat  = ws + off; off += (size_t)4 * WCAT_SZ; // [l*2+t]
    int* iws = (int*)(ws + off);
    size_t ioff = 0;
    int* rp_cd   = iws + ioff; ioff += NN_ + 1;
    int* rp_dc   = iws + ioff; ioff += NN_ + 1;
    int* srcs_cd = iws + ioff; ioff += E_CNT;
    int* srcs_dc = iws + ioff; ioff += E_CNT;
    int* cnt     = iws + ioff; ioff += NN_;
    int* cursor  = iws + ioff; ioff += NN_;
    int* partial = iws + ioff; ioff += 128;
    float* zC = kv;                                      // reuse after edge phases
    float* zD = kv + (size_t)NN_ * 128;

    const int gridM = (NN_ + 127) / 128;          // 782
    const int gE    = (E_CNT + 255) / 256;
    const int gN    = (NN_ + 255) / 256;
    const int gScan = 98;
    const int gGath = (NN_ + 3) / 4;              // 4 waves/block

    // ---- build CSR for both relations ----
    {
        const int* srcsA[2] = { ei_cd, ei_dc };
        const int* dstsA[2] = { ei_cd + E_CNT, ei_dc + E_CNT };
        int* rps[2]  = { rp_cd, rp_dc };
        int* outs[2] = { srcs_cd, srcs_dc };
        for (int r = 0; r < 2; r++) {
            fill0_int<<<gN, 256, 0, stream>>>(cnt, NN_);
            count_dst<<<gE, 256, 0, stream>>>(dstsA[r], cnt);
            scan_a<<<gScan, 256, 0, stream>>>(cnt, rps[r], partial);
            scan_b<<<1, 128, 0, stream>>>(partial);
            scan_c<<<gScan, 256, 0, stream>>>(rps[r], partial, cursor);
            scatter_edges<<<gE, 256, 0, stream>>>(srcsA[r], dstsA[r], cursor, outs[r]);
        }
    }

    // ---- all weight fusion in one launch (both layers, both types) ----
    fuse_weights<<<dim3(129, 2, 2), 384, 0, stream>>>(qW, qb, kW, kb, vW, vb,
                                                      arel, mrel, Wcat);

    for (int l = 0; l < 2; l++) {
        const float* aWl = aW + (size_t)l * 2 * 128 * 128;
        const float* abl = ab + (size_t)l * 2 * 128;
        float* WcC = Wcat + (size_t)(l * 2 + 0) * WCAT_SZ;
        float* WcD = Wcat + (size_t)(l * 2 + 1) * WCAT_SZ;

        // ---- relation 0: C -> D ----  (dual: kvC y0-1, qD y2)
        gemm2<128, 0, 0><<<dim3(gridM, 3), 256, 0, stream>>>(
            xC, 128, WcC + 128, 384, WcC + 128 * 384 + 128, kv, 256, NC_, nullptr, nullptr,
            2, xD, WcD, WcD + 128 * 384, qo, 128);
        attn_gather<<<gGath, 256, 0, stream>>>(rp_cd, srcs_cd, qo, kv,
                                               prel + (l * 2 + 0) * 4, ND_);  // outD in qo

        // kvD from OLD xD (before epilogue D overwrites it)
        gemm2<128, 0, 0><<<dim3(gridM, 2), 256, 0, stream>>>(
            xD, 128, WcD + 128, 384, WcD + 128 * 384 + 128, kv, 256, ND_, nullptr, nullptr,
            -1, nullptr, nullptr, nullptr, nullptr, 0);

        // epilogue D: xD = relu(g*(gelu(outD)@aW_D+ab_D) + (1-g)*xD)
        gemm2<128, 1, 1><<<dim3(gridM, 1), 256, 0, stream>>>(
            qo, 128, aWl + 128 * 128, 128, abl + 128, xD, 128, ND_, xD, skip + l * 2 + 1,
            -1, nullptr, nullptr, nullptr, nullptr, 0);

        // ---- relation 1: D -> C ----
        gemm2<128, 0, 0><<<dim3(gridM, 1), 256, 0, stream>>>(     // qC (old xC)
            xC, 128, WcC, 384, WcC + 128 * 384, qo, 128, NC_, nullptr, nullptr,
            -1, nullptr, nullptr, nullptr, nullptr, 0);
        attn_gather<<<gGath, 256, 0, stream>>>(rp_dc, srcs_dc, qo, kv,
                                               prel + (l * 2 + 1) * 4, NC_);  // outC in qo

        // epilogue C
        gemm2<128, 1, 1><<<dim3(gridM, 1), 256, 0, stream>>>(
            qo, 128, aWl, 128, abl, xC, 128, NC_, xC, skip + l * 2 + 0,
            -1, nullptr, nullptr, nullptr, nullptr, 0);
    }

    // final projections z = x @ outW + outb  ([N,128] @ [128,64]), both types dual
    gemm2<64, 0, 0><<<dim3(gridM, 2), 256, 0, stream>>>(
        xC, 128, outW, 64, outb, zC, 64, NC_, nullptr, nullptr,
        1, xD, outW + 128 * 64, outb + 64, zD, 64);

    score_pairs<<<(L_CNT * 16 + 255) / 256, 256, 0, stream>>>(
        eli, eli + L_CNT, zC, zD, (float*)d_out);
}